// Round 10
// baseline (196.141 us; speedup 1.0000x reference)
//
#include <hip/hip_runtime.h>

typedef __bf16 bf16;
typedef __bf16 bf16x4 __attribute__((ext_vector_type(4)));
typedef __bf16 bf16x8 __attribute__((ext_vector_type(8)));
typedef _Float16 f16;
typedef _Float16 f16x4 __attribute__((ext_vector_type(4)));
typedef _Float16 f16x8 __attribute__((ext_vector_type(8)));
typedef float f32x4 __attribute__((ext_vector_type(4)));
typedef unsigned int uint2t __attribute__((ext_vector_type(2)));
typedef unsigned int uint4t __attribute__((ext_vector_type(4)));

#define MFMA16(a, b, c) __builtin_amdgcn_mfma_f32_16x16x32_bf16(a, b, c, 0, 0, 0)
#define MFMA16F(a, b, c) __builtin_amdgcn_mfma_f32_16x16x32_f16(a, b, c, 0, 0, 0)

// async global->LDS DMA, 16B/lane; LDS dest = wave-uniform base + lane*16.
__device__ __forceinline__ void lds_load16(void* lds, const void* g) {
  __builtin_amdgcn_global_load_lds(
      (const __attribute__((address_space(1))) unsigned int*)g,
      (__attribute__((address_space(3))) unsigned int*)lds, 16, 0, 0);
}

// fp32 -> {bf16, bf16, f16} bulk convert, all three tensors in one launch.
// out_w goes to f16 (10 mantissa bits vs bf16's 7): |w|<=0.031, f16-safe.
__global__ void cvt3(const float* __restrict__ x, const float* __restrict__ qw,
                     const float* __restrict__ ow, bf16* __restrict__ xb,
                     bf16* __restrict__ qwb, f16* __restrict__ owb) {
  const int i = blockIdx.x * blockDim.x + threadIdx.x;  // 0..2097151
  if (i < 1048576 + 786432) {
    const float* src;
    bf16* dst;
    int k;
    if (i < 1048576) {
      src = x; dst = xb; k = i;
    } else {
      src = qw; dst = qwb; k = i - 1048576;
    }
    const float4 v = ((const float4*)src)[k];
    bf16x4 o;
    o[0] = (bf16)v.x; o[1] = (bf16)v.y; o[2] = (bf16)v.z; o[3] = (bf16)v.w;
    ((bf16x4*)dst)[k] = o;
  } else {
    const int k = i - (1048576 + 786432);
    const float4 v = ((const float4*)ow)[k];
    f16x4 o;
    o[0] = (f16)v.x; o[1] = (f16)v.y; o[2] = (f16)v.z; o[3] = (f16)v.w;
    ((f16x4*)owb)[k] = o;
  }
}

// QKV GEMM, 16x16 MFMA + XOR chunk-swizzled LDS.
//   col<1024  -> Qb[t][col] bf16, PRE-SCALED by 0.125*log2(e)
//   col<2048  -> KF fragment-native bf16 (attn A-frag = base + lane*16B)
//   col>=2048 -> VF fragment-native **f16**, x4-packed along t
__global__ __launch_bounds__(256, 3) void gemm_qkv(
    const bf16* __restrict__ A, const bf16* __restrict__ B,
    const float* __restrict__ bias, bf16* __restrict__ Qb,
    bf16* __restrict__ KF, f16* __restrict__ VF) {
  const int K = 1024;
  __shared__ bf16 As[128][64];
  __shared__ bf16 Bs[128][64];
  const int tid = threadIdx.x;
  const int w = tid >> 6, lane = tid & 63;
  const int l15 = lane & 15, quad = lane >> 4;
  const int lr = lane >> 3;  // row within 8-row DMA chunk (= actual_row & 7)
  const int lcs = ((lane & 7) ^ lr) * 8;  // swizzled source col for DMA
  const int sw = l15 & 7;                 // fragment-row & 7 for read side
  const int blk = blockIdx.x;             // 0..767 linear
  const int xslot = blk & 7, rest = blk >> 3;  // rest 0..95
  const int bm = xslot * 4 + (rest & 3);       // 0..31
  const int bn = rest >> 2;                    // 0..23
  const int wm = (w >> 1) * 64, wn = (w & 1) * 64;

  const bf16* Abase = A + (size_t)(bm * 128) * K;
  const bf16* Bbase = B + (size_t)(bn * 128) * K;

  f32x4 acc[4][4] = {};

  for (int k0 = 0; k0 < K; k0 += 64) {
#pragma unroll
    for (int c = 0; c < 4; ++c) {
      const int row = w * 32 + c * 8;  // ≡0 mod 8 -> (row+lr)&7 == lr
      lds_load16(&As[row][0], Abase + (size_t)(row + lr) * K + k0 + lcs);
      lds_load16(&Bs[row][0], Bbase + (size_t)(row + lr) * K + k0 + lcs);
    }
    __syncthreads();
#pragma unroll
    for (int kk = 0; kk < 64; kk += 32) {
      const int cb = kk >> 3;  // logical chunk base: 0 or 4
      bf16x8 am[4], bnf[4];
#pragma unroll
      for (int i = 0; i < 4; ++i)
        am[i] = *(const bf16x8*)&As[wm + i * 16 + l15][((cb + quad) ^ sw) * 8];
#pragma unroll
      for (int j = 0; j < 4; ++j)
        bnf[j] = *(const bf16x8*)&Bs[wn + j * 16 + l15][((cb + quad) ^ sw) * 8];
#pragma unroll
      for (int i = 0; i < 4; ++i)
#pragma unroll
        for (int j = 0; j < 4; ++j)
          acc[i][j] = MFMA16(am[i], bnf[j], acc[i][j]);
    }
    __syncthreads();
  }

  // epilogue: C/D layout col=lane&15, row=quad*4+reg
#pragma unroll
  for (int j = 0; j < 4; ++j) {
    const int gcol = bn * 128 + wn + j * 16 + l15;
    const float bv = bias[gcol];
#pragma unroll
    for (int i = 0; i < 4; ++i) {
      const int t0 = bm * 128 + wm + i * 16 + quad * 4;  // r-consecutive rows
      if (gcol < 1024) {
#pragma unroll
        for (int r = 0; r < 4; ++r)
          Qb[(size_t)(t0 + r) * 1024 + gcol] =
              (bf16)((acc[i][j][r] + bv) * 0.18033688f);  // 0.125*log2e
      } else if (gcol < 2048) {
        const int dhl = gcol - 1024;  // 0..1023
        const int hh = dhl >> 6, dh = dhl & 63;
        const int tl = t0 & 2047, bb = t0 >> 11;
        const size_t frag = ((size_t)(bb * 16 + hh) * 32 + (tl >> 6)) * 8 +
                            ((tl & 63) >> 4) * 2 + (dh >> 5);
        bf16* p = &KF[frag * 512 +
                      (size_t)(((dh >> 3) & 3) * 16 + (tl & 15)) * 8 + (dh & 7)];
#pragma unroll
        for (int r = 0; r < 4; ++r) p[r * 8] = (bf16)(acc[i][j][r] + bv);
      } else {
        const int dhl = gcol - 2048;
        const int hh = dhl >> 6, dh = dhl & 63;
        const int tl = t0 & 2047, bb = t0 >> 11;
        const size_t frag = ((size_t)(bb * 16 + hh) * 32 + (tl >> 6)) * 8 +
                            (dh >> 4) * 2 + ((tl & 63) >> 5);
        f16x4 pv;
#pragma unroll
        for (int r = 0; r < 4; ++r) pv[r] = (f16)(acc[i][j][r] + bv);
        *(f16x4*)&VF[frag * 512 +
                     (size_t)(((tl & 31) >> 3) * 16 + (dh & 15)) * 8 +
                     (tl & 7)] = pv;
      }
    }
  }
}

// Out-proj GEMM, 64x128 tile, same XOR chunk-swizzle. A=ctx, B=out_w in f16.
__global__ __launch_bounds__(256, 2) void gemm_out(
    const f16* __restrict__ A, const f16* __restrict__ B,
    const float* __restrict__ bias, float* __restrict__ Cf) {
  __shared__ f16 As[64][64];
  __shared__ f16 Bs[128][64];
  const int tid = threadIdx.x;
  const int w = tid >> 6, lane = tid & 63;
  const int l15 = lane & 15, quad = lane >> 4;
  const int lr = lane >> 3;
  const int lcs = ((lane & 7) ^ lr) * 8;  // swizzled DMA source col
  const int sw = l15 & 7;
  const int blk = blockIdx.x;  // 0..511 linear
  const int xslot = blk & 7, rest = blk >> 3;  // rest 0..63
  const int bm = xslot * 8 + (rest & 7);       // 0..63
  const int bn = rest >> 3;                    // 0..7

  const f16* Abase = A + (size_t)(bm * 64) * 1024;
  const f16* Bbase = B + (size_t)(bn * 128) * 1024;

  f32x4 acc[4][2] = {};

  for (int k0 = 0; k0 < 1024; k0 += 64) {
#pragma unroll
    for (int c = 0; c < 2; ++c) {
      const int row = w * 16 + c * 8;
      lds_load16(&As[row][0], Abase + (size_t)(row + lr) * 1024 + k0 + lcs);
    }
#pragma unroll
    for (int c = 0; c < 4; ++c) {
      const int row = w * 32 + c * 8;
      lds_load16(&Bs[row][0], Bbase + (size_t)(row + lr) * 1024 + k0 + lcs);
    }
    __syncthreads();
#pragma unroll
    for (int kk = 0; kk < 64; kk += 32) {
      const int cb = kk >> 3;
      f16x8 am[4], bnf[2];
#pragma unroll
      for (int i = 0; i < 4; ++i)
        am[i] = *(const f16x8*)&As[i * 16 + l15][((cb + quad) ^ sw) * 8];
#pragma unroll
      for (int j = 0; j < 2; ++j)
        bnf[j] =
            *(const f16x8*)&Bs[w * 32 + j * 16 + l15][((cb + quad) ^ sw) * 8];
#pragma unroll
      for (int i = 0; i < 4; ++i)
#pragma unroll
        for (int j = 0; j < 2; ++j)
          acc[i][j] = MFMA16F(am[i], bnf[j], acc[i][j]);
    }
    __syncthreads();
  }

#pragma unroll
  for (int j = 0; j < 2; ++j) {
    const int gcol = bn * 128 + w * 32 + j * 16 + l15;
    const float bv = bias[gcol];
#pragma unroll
    for (int i = 0; i < 4; ++i)
#pragma unroll
      for (int r = 0; r < 4; ++r) {
        const int grow = bm * 64 + i * 16 + quad * 4 + r;
        Cf[(size_t)grow * 1024 + gcol] = acc[i][j][r] + bv;
      }
  }
}

// Flash attention v17: v16 minus V-in-LDS (Common-mistake #7 / m169).
// r9 audit: LDS is attn's most-loaded pipe (~3600 cyc/CU-iter of 6450:
// 256KB reads + 64KB DMA writes; MFMA ~700/SIMD, VALU+TRANS ~1100/SIMD).
// V is consumed ONCE per wave-iter as PV A-frags and is L2-resident
// (256KB per (b,h); XCD slot-swizzle pins each bh's V to one XCD's 4MB L2).
// So: read av straight from global with the SAME addresses/bytes as the old
// LDS path — zero layout change, bit-identical output. Deletes 8 ds_read
// + 2 V-DMAs per wave-iter (LDS traffic -45%); av loads issued BEFORE QK^T
// so ~200cy L2 latency hides under ~2000cy of QK+softmax. LDS drops to
// 35KB (K ping-pong 32KB, overlaid with the 35KB combine scratch).
__global__ __launch_bounds__(512, 4) void attn(const bf16* __restrict__ Qb,
                                               const bf16* __restrict__ KF,
                                               const f16* __restrict__ VF,
                                               f16* __restrict__ CTX) {
  // 35328 B: K tiles [group][pingpong][4096] bf16 (32KB) overlaid with the
  // end-of-kernel combine scratch ob[128][68] f32 + lb[128] f32 (35.3KB).
  __shared__ __align__(16) char smem[35328];
  bf16* Kb = (bf16*)smem;
  const int tid = threadIdx.x, w = tid >> 6, lane = tid & 63;
  const int g = w >> 2, wg = w & 3;  // key-group, q-band wave
  const int l15 = lane & 15, quad = lane >> 4;
  const int blk = blockIdx.x;
  const int slot = blk & 7, grp = blk >> 3;
  const int qt = grp & 15, bh = (grp >> 4) * 8 + slot;  // bh 0..31
  const int h = bh & 15, b = bh >> 4;
  const int q0 = qt * 128;

  const bf16* qrow0 =
      Qb + (size_t)(b * 2048 + q0 + wg * 32 + l15) * 1024 + h * 64;
  const bf16* qrow1 = qrow0 + (size_t)16 * 1024;
  const bf16x8 bq0a = *(const bf16x8*)&qrow0[quad * 8];
  const bf16x8 bq0b = *(const bf16x8*)&qrow0[32 + quad * 8];
  const bf16x8 bq1a = *(const bf16x8*)&qrow1[quad * 8];
  const bf16x8 bq1b = *(const bf16x8*)&qrow1[32 + quad * 8];

  const bf16* kfs = KF + (size_t)(b * 16 + h) * 131072 + (size_t)g * 65536;
  const f16* vfs = VF + (size_t)(b * 16 + h) * 131072 + (size_t)g * 65536;
  const int so = wg * 1024;  // 4 waves x 2 chunks x 512 cover the 8KB K tile

#pragma unroll
  for (int c = 0; c < 2; ++c)
    lds_load16(&Kb[g * 8192 + so + c * 512], kfs + so + c * 512 + lane * 8);

  const f16x8 ones8 = {(f16)1, (f16)1, (f16)1, (f16)1,
                       (f16)1, (f16)1, (f16)1, (f16)1};
  f32x4 lsum[2] = {};  // D[r][q=l15]: per-q denominator, all r identical
  f32x4 o[2][4] = {};

  for (int kt = 0; kt < 16; ++kt) {
    const int cur = kt & 1;
    const bf16* kcur = &Kb[(g * 2 + cur) * 4096];
    __syncthreads();

    if (kt < 15) {
      const size_t nb = (size_t)(kt + 1) * 4096;
#pragma unroll
      for (int c = 0; c < 2; ++c)
        lds_load16(&Kb[(g * 2 + (cur ^ 1)) * 4096 + so + c * 512],
                   kfs + nb + so + c * 512 + lane * 8);
    }

    // V fragments for THIS tile straight from global (L2-resident).
    // Issued before QK so the ~200cy latency hides under QK+softmax.
    const f16* vt = vfs + (size_t)kt * 4096 + lane * 8;
    f16x8 av[2][4];
#pragma unroll
    for (int k2 = 0; k2 < 2; ++k2)
#pragma unroll
      for (int j = 0; j < 4; ++j)
        av[k2][j] = *(const f16x8*)&vt[(j * 2 + k2) * 512];

    f32x4 s[2][4] = {};
    __builtin_amdgcn_s_setprio(1);
#pragma unroll
    for (int k2 = 0; k2 < 2; ++k2)
#pragma unroll
      for (int j = 0; j < 4; ++j) {
        const bf16x8 ak = *(const bf16x8*)&kcur[(j * 2 + k2) * 512 + lane * 8];
        s[0][j] = MFMA16(ak, k2 ? bq0b : bq0a, s[0][j]);
        s[1][j] = MFMA16(ak, k2 ? bq1b : bq1a, s[1][j]);
      }
    __builtin_amdgcn_s_setprio(0);

    // in-register softmax + P redistribution, VALU-minimal.
    f16x8 bp[2][2];  // [q-group][k2]
#pragma unroll
    for (int i = 0; i < 2; ++i) {
      uint2t pd[4];
#pragma unroll
      for (int j = 0; j < 4; ++j) {
        const auto lo =
            __builtin_amdgcn_cvt_pkrtz(__builtin_amdgcn_exp2f(s[i][j][0]),
                                       __builtin_amdgcn_exp2f(s[i][j][1]));
        const auto hi =
            __builtin_amdgcn_cvt_pkrtz(__builtin_amdgcn_exp2f(s[i][j][2]),
                                       __builtin_amdgcn_exp2f(s[i][j][3]));
        pd[j][0] = __builtin_bit_cast(unsigned, lo);
        pd[j][1] = __builtin_bit_cast(unsigned, hi);
      }
#pragma unroll
      for (int k2 = 0; k2 < 2; ++k2) {
        uint4t wd;
#pragma unroll
        for (int d = 0; d < 2; ++d) {
          unsigned pa = pd[2 * k2][d], pb = pd[2 * k2 + 1][d];
          asm("v_permlane32_swap_b32 %0, %1" : "+v"(pa), "+v"(pb));
          asm("v_permlane16_swap_b32 %0, %1" : "+v"(pa), "+v"(pb));
          wd[d] = pa;      // bp elements e=0..3 (dword d)
          wd[2 + d] = pb;  // bp elements e=4..7 (dword d)
        }
        bp[i][k2] = __builtin_bit_cast(f16x8, wd);
      }
    }

    __builtin_amdgcn_s_setprio(1);
#pragma unroll
    for (int k2 = 0; k2 < 2; ++k2) {
#pragma unroll
      for (int j = 0; j < 4; ++j) {
        o[0][j] = MFMA16F(av[k2][j], bp[0][k2], o[0][j]);
        o[1][j] = MFMA16F(av[k2][j], bp[1][k2], o[1][j]);
      }
      // denominator: sums the exact f16 P consumed above (MFMA pipe, free)
      lsum[0] = MFMA16F(ones8, bp[0][k2], lsum[0]);
      lsum[1] = MFMA16F(ones8, bp[1][k2], lsum[1]);
    }
    __builtin_amdgcn_s_setprio(0);
  }

  // in-block combine of the two key-halves; K LDS is dead, reuse it.
  __syncthreads();
  float* ob = (float*)smem;             // [128][68] f32 (padded, 16B rows)
  float* lb = (float*)(smem + 34816);   // [128] f32
  if (g == 1) {
#pragma unroll
    for (int i = 0; i < 2; ++i) {
      const int q = wg * 32 + i * 16 + l15;
#pragma unroll
      for (int j = 0; j < 4; ++j)
        *(f32x4*)&ob[q * 68 + j * 16 + quad * 4] = o[i][j];
      if (quad == 0) lb[q] = lsum[i][0];
    }
  }
  __syncthreads();
  if (g == 0) {
#pragma unroll
    for (int i = 0; i < 2; ++i) {
      const int q = wg * 32 + i * 16 + l15;
      const float inv = 1.f / (lsum[i][0] + lb[q]);
      f16* crow = CTX + (size_t)(b * 2048 + q0 + q) * 1024 + h * 64;
#pragma unroll
      for (int j = 0; j < 4; ++j) {
        const f32x4 ox = o[i][j] + *(const f32x4*)&ob[q * 68 + j * 16 + quad * 4];
        f16x4 ov;
#pragma unroll
        for (int r = 0; r < 4; ++r) ov[r] = (f16)(ox[r] * inv);
        *(f16x4*)&crow[j * 16 + quad * 4] = ov;
      }
    }
  }
}

extern "C" void kernel_launch(void* const* d_in, const int* in_sizes, int n_in,
                              void* d_out, int out_size, void* d_ws,
                              size_t ws_size, hipStream_t stream) {
  const float* x = (const float*)d_in[0];      // [2,2048,1024] fp32
  const float* qkv_w = (const float*)d_in[1];  // [3072,1024] fp32
  const float* qkv_b = (const float*)d_in[2];  // [3072] fp32
  const float* out_w = (const float*)d_in[3];  // [1024,1024] fp32
  const float* out_b = (const float*)d_in[4];  // [1024] fp32
  float* out = (float*)d_out;                  // [2,2048,1024] fp32

  // ws (2B elems): xb 8MB | wqkv 6MB | wout 2MB | qb 8 | KF 8 | VF 8 | ctx 8
  bf16* base = (bf16*)d_ws;
  bf16* xb = base;                                    // [4096][1024] bf16
  bf16* wqkv = base + (size_t)4096 * 1024;            // [3072][1024] bf16
  f16* wout = (f16*)(base + (size_t)7168 * 1024);     // [1024][1024] f16
  bf16* qb = base + (size_t)8192 * 1024;              // [4096][1024] bf16
  bf16* kf = base + (size_t)12288 * 1024;             // frag-native K bf16
  f16* vf = (f16*)(base + (size_t)16384 * 1024);      // frag-native V^T f16
  f16* ctx = (f16*)(base + (size_t)20480 * 1024);     // [4096][1024] f16

  cvt3<<<2097152 / 256, 256, 0, stream>>>(x, qkv_w, out_w, xb, wqkv, wout);

  gemm_qkv<<<768, 256, 0, stream>>>(xb, wqkv, qkv_b, qb, kf, vf);
  attn<<<512, 512, 0, stream>>>(qb, kf, vf, ctx);
  gemm_out<<<512, 256, 0, stream>>>(ctx, wout, out_b, out);
}

// Round 11
// 171.382 us; speedup vs baseline: 1.1445x; 1.1445x over previous
//
#include <hip/hip_runtime.h>

typedef __bf16 bf16;
typedef __bf16 bf16x4 __attribute__((ext_vector_type(4)));
typedef __bf16 bf16x8 __attribute__((ext_vector_type(8)));
typedef _Float16 f16;
typedef _Float16 f16x4 __attribute__((ext_vector_type(4)));
typedef _Float16 f16x8 __attribute__((ext_vector_type(8)));
typedef float f32x4 __attribute__((ext_vector_type(4)));
typedef unsigned int uint2t __attribute__((ext_vector_type(2)));
typedef unsigned int uint4t __attribute__((ext_vector_type(4)));

#define MFMA16(a, b, c) __builtin_amdgcn_mfma_f32_16x16x32_bf16(a, b, c, 0, 0, 0)
#define MFMA16F(a, b, c) __builtin_amdgcn_mfma_f32_16x16x32_f16(a, b, c, 0, 0, 0)

// async global->LDS DMA, 16B/lane; LDS dest = wave-uniform base + lane*16.
__device__ __forceinline__ void lds_load16(void* lds, const void* g) {
  __builtin_amdgcn_global_load_lds(
      (const __attribute__((address_space(1))) unsigned int*)g,
      (__attribute__((address_space(3))) unsigned int*)lds, 16, 0, 0);
}

// fp32 -> {bf16, bf16, f16} bulk convert, all three tensors in one launch.
// out_w goes to f16 (10 mantissa bits vs bf16's 7): |w|<=0.031, f16-safe.
__global__ void cvt3(const float* __restrict__ x, const float* __restrict__ qw,
                     const float* __restrict__ ow, bf16* __restrict__ xb,
                     bf16* __restrict__ qwb, f16* __restrict__ owb) {
  const int i = blockIdx.x * blockDim.x + threadIdx.x;  // 0..2097151
  if (i < 1048576 + 786432) {
    const float* src;
    bf16* dst;
    int k;
    if (i < 1048576) {
      src = x; dst = xb; k = i;
    } else {
      src = qw; dst = qwb; k = i - 1048576;
    }
    const float4 v = ((const float4*)src)[k];
    bf16x4 o;
    o[0] = (bf16)v.x; o[1] = (bf16)v.y; o[2] = (bf16)v.z; o[3] = (bf16)v.w;
    ((bf16x4*)dst)[k] = o;
  } else {
    const int k = i - (1048576 + 786432);
    const float4 v = ((const float4*)ow)[k];
    f16x4 o;
    o[0] = (f16)v.x; o[1] = (f16)v.y; o[2] = (f16)v.z; o[3] = (f16)v.w;
    ((f16x4*)owb)[k] = o;
  }
}

// QKV GEMM, 16x16 MFMA + XOR chunk-swizzled LDS.
//   col<1024  -> Qb[t][col] bf16, PRE-SCALED by 0.125*log2(e)
//   col<2048  -> KF fragment-native bf16 (attn A-frag = base + lane*16B)
//   col>=2048 -> VF fragment-native **f16**, x4-packed along t
__global__ __launch_bounds__(256, 3) void gemm_qkv(
    const bf16* __restrict__ A, const bf16* __restrict__ B,
    const float* __restrict__ bias, bf16* __restrict__ Qb,
    bf16* __restrict__ KF, f16* __restrict__ VF) {
  const int K = 1024;
  __shared__ bf16 As[128][64];
  __shared__ bf16 Bs[128][64];
  const int tid = threadIdx.x;
  const int w = tid >> 6, lane = tid & 63;
  const int l15 = lane & 15, quad = lane >> 4;
  const int lr = lane >> 3;  // row within 8-row DMA chunk (= actual_row & 7)
  const int lcs = ((lane & 7) ^ lr) * 8;  // swizzled source col for DMA
  const int sw = l15 & 7;                 // fragment-row & 7 for read side
  const int blk = blockIdx.x;             // 0..767 linear
  const int xslot = blk & 7, rest = blk >> 3;  // rest 0..95
  const int bm = xslot * 4 + (rest & 3);       // 0..31
  const int bn = rest >> 2;                    // 0..23
  const int wm = (w >> 1) * 64, wn = (w & 1) * 64;

  const bf16* Abase = A + (size_t)(bm * 128) * K;
  const bf16* Bbase = B + (size_t)(bn * 128) * K;

  f32x4 acc[4][4] = {};

  for (int k0 = 0; k0 < K; k0 += 64) {
#pragma unroll
    for (int c = 0; c < 4; ++c) {
      const int row = w * 32 + c * 8;  // ≡0 mod 8 -> (row+lr)&7 == lr
      lds_load16(&As[row][0], Abase + (size_t)(row + lr) * K + k0 + lcs);
      lds_load16(&Bs[row][0], Bbase + (size_t)(row + lr) * K + k0 + lcs);
    }
    __syncthreads();
#pragma unroll
    for (int kk = 0; kk < 64; kk += 32) {
      const int cb = kk >> 3;  // logical chunk base: 0 or 4
      bf16x8 am[4], bnf[4];
#pragma unroll
      for (int i = 0; i < 4; ++i)
        am[i] = *(const bf16x8*)&As[wm + i * 16 + l15][((cb + quad) ^ sw) * 8];
#pragma unroll
      for (int j = 0; j < 4; ++j)
        bnf[j] = *(const bf16x8*)&Bs[wn + j * 16 + l15][((cb + quad) ^ sw) * 8];
#pragma unroll
      for (int i = 0; i < 4; ++i)
#pragma unroll
        for (int j = 0; j < 4; ++j)
          acc[i][j] = MFMA16(am[i], bnf[j], acc[i][j]);
    }
    __syncthreads();
  }

  // epilogue: C/D layout col=lane&15, row=quad*4+reg
#pragma unroll
  for (int j = 0; j < 4; ++j) {
    const int gcol = bn * 128 + wn + j * 16 + l15;
    const float bv = bias[gcol];
#pragma unroll
    for (int i = 0; i < 4; ++i) {
      const int t0 = bm * 128 + wm + i * 16 + quad * 4;  // r-consecutive rows
      if (gcol < 1024) {
#pragma unroll
        for (int r = 0; r < 4; ++r)
          Qb[(size_t)(t0 + r) * 1024 + gcol] =
              (bf16)((acc[i][j][r] + bv) * 0.18033688f);  // 0.125*log2e
      } else if (gcol < 2048) {
        const int dhl = gcol - 1024;  // 0..1023
        const int hh = dhl >> 6, dh = dhl & 63;
        const int tl = t0 & 2047, bb = t0 >> 11;
        const size_t frag = ((size_t)(bb * 16 + hh) * 32 + (tl >> 6)) * 8 +
                            ((tl & 63) >> 4) * 2 + (dh >> 5);
        bf16* p = &KF[frag * 512 +
                      (size_t)(((dh >> 3) & 3) * 16 + (tl & 15)) * 8 + (dh & 7)];
#pragma unroll
        for (int r = 0; r < 4; ++r) p[r * 8] = (bf16)(acc[i][j][r] + bv);
      } else {
        const int dhl = gcol - 2048;
        const int hh = dhl >> 6, dh = dhl & 63;
        const int tl = t0 & 2047, bb = t0 >> 11;
        const size_t frag = ((size_t)(bb * 16 + hh) * 32 + (tl >> 6)) * 8 +
                            (dh >> 4) * 2 + ((tl & 63) >> 5);
        f16x4 pv;
#pragma unroll
        for (int r = 0; r < 4; ++r) pv[r] = (f16)(acc[i][j][r] + bv);
        *(f16x4*)&VF[frag * 512 +
                     (size_t)(((tl & 31) >> 3) * 16 + (dh & 15)) * 8 +
                     (tl & 7)] = pv;
      }
    }
  }
}

// Out-proj GEMM, 64x128 tile, same XOR chunk-swizzle. A=ctx, B=out_w in f16.
__global__ __launch_bounds__(256, 2) void gemm_out(
    const f16* __restrict__ A, const f16* __restrict__ B,
    const float* __restrict__ bias, float* __restrict__ Cf) {
  __shared__ f16 As[64][64];
  __shared__ f16 Bs[128][64];
  const int tid = threadIdx.x;
  const int w = tid >> 6, lane = tid & 63;
  const int l15 = lane & 15, quad = lane >> 4;
  const int lr = lane >> 3;
  const int lcs = ((lane & 7) ^ lr) * 8;  // swizzled DMA source col
  const int sw = l15 & 7;
  const int blk = blockIdx.x;  // 0..511 linear
  const int xslot = blk & 7, rest = blk >> 3;  // rest 0..63
  const int bm = xslot * 8 + (rest & 7);       // 0..63
  const int bn = rest >> 3;                    // 0..7

  const f16* Abase = A + (size_t)(bm * 64) * 1024;
  const f16* Bbase = B + (size_t)(bn * 128) * 1024;

  f32x4 acc[4][2] = {};

  for (int k0 = 0; k0 < 1024; k0 += 64) {
#pragma unroll
    for (int c = 0; c < 2; ++c) {
      const int row = w * 16 + c * 8;
      lds_load16(&As[row][0], Abase + (size_t)(row + lr) * 1024 + k0 + lcs);
    }
#pragma unroll
    for (int c = 0; c < 4; ++c) {
      const int row = w * 32 + c * 8;
      lds_load16(&Bs[row][0], Bbase + (size_t)(row + lr) * 1024 + k0 + lcs);
    }
    __syncthreads();
#pragma unroll
    for (int kk = 0; kk < 64; kk += 32) {
      const int cb = kk >> 3;
      f16x8 am[4], bnf[2];
#pragma unroll
      for (int i = 0; i < 4; ++i)
        am[i] = *(const f16x8*)&As[i * 16 + l15][((cb + quad) ^ sw) * 8];
#pragma unroll
      for (int j = 0; j < 2; ++j)
        bnf[j] =
            *(const f16x8*)&Bs[w * 32 + j * 16 + l15][((cb + quad) ^ sw) * 8];
#pragma unroll
      for (int i = 0; i < 4; ++i)
#pragma unroll
        for (int j = 0; j < 2; ++j)
          acc[i][j] = MFMA16F(am[i], bnf[j], acc[i][j]);
    }
    __syncthreads();
  }

#pragma unroll
  for (int j = 0; j < 2; ++j) {
    const int gcol = bn * 128 + w * 32 + j * 16 + l15;
    const float bv = bias[gcol];
#pragma unroll
    for (int i = 0; i < 4; ++i)
#pragma unroll
      for (int r = 0; r < 4; ++r) {
        const int grow = bm * 64 + i * 16 + quad * 4 + r;
        Cf[(size_t)grow * 1024 + gcol] = acc[i][j][r] + bv;
      }
  }
}

// Flash attention v18: V-from-global, SPILL-FREE placement.
// r10 post-mortem: v17 regressed 43->75.6us. Smoking gun: WRITE_SIZE 8->56MB
// (+48MB = 192B/thread of SCRATCH traffic), VGPR pinned at 64. Loading
// av[2][4] (32 VGPRs) BEFORE QK^T made it live across QK^T (s[2][4] also
// live, 32 regs) + softmax -> peak ~135 > 128 cap (launch_bounds 512,4) ->
// allocator spilled av. The V-from-global mechanism was not refuted; the
// PLACEMENT was wrong.
// v18: av loads issued AFTER softmax/bp (s is dead there). Peak pressure:
// QK-phase ~100, PV-phase ~104 — both <=128, no spill. V is L2-resident
// (4 bh x 256KB = 1MB per XCD's 4MB L2, pinned by the slot swizzle); the
// batch of 8 loads gets counted-vmcnt waits and 4 waves/SIMD TLP covers
// the ~200cy first-use stall. LDS pipe traffic still -45% vs v16.
// Check on next profile: WRITE_SIZE==8192 (spill gone), VGPR ~90-110.
__global__ __launch_bounds__(512, 4) void attn(const bf16* __restrict__ Qb,
                                               const bf16* __restrict__ KF,
                                               const f16* __restrict__ VF,
                                               f16* __restrict__ CTX) {
  // 35328 B: K tiles [group][pingpong][4096] bf16 (32KB) overlaid with the
  // end-of-kernel combine scratch ob[128][68] f32 + lb[128] f32 (35.3KB).
  __shared__ __align__(16) char smem[35328];
  bf16* Kb = (bf16*)smem;
  const int tid = threadIdx.x, w = tid >> 6, lane = tid & 63;
  const int g = w >> 2, wg = w & 3;  // key-group, q-band wave
  const int l15 = lane & 15, quad = lane >> 4;
  const int blk = blockIdx.x;
  const int slot = blk & 7, grp = blk >> 3;
  const int qt = grp & 15, bh = (grp >> 4) * 8 + slot;  // bh 0..31
  const int h = bh & 15, b = bh >> 4;
  const int q0 = qt * 128;

  const bf16* qrow0 =
      Qb + (size_t)(b * 2048 + q0 + wg * 32 + l15) * 1024 + h * 64;
  const bf16* qrow1 = qrow0 + (size_t)16 * 1024;
  const bf16x8 bq0a = *(const bf16x8*)&qrow0[quad * 8];
  const bf16x8 bq0b = *(const bf16x8*)&qrow0[32 + quad * 8];
  const bf16x8 bq1a = *(const bf16x8*)&qrow1[quad * 8];
  const bf16x8 bq1b = *(const bf16x8*)&qrow1[32 + quad * 8];

  const bf16* kfs = KF + (size_t)(b * 16 + h) * 131072 + (size_t)g * 65536;
  const f16* vfs = VF + (size_t)(b * 16 + h) * 131072 + (size_t)g * 65536;
  const int so = wg * 1024;  // 4 waves x 2 chunks x 512 cover the 8KB K tile

#pragma unroll
  for (int c = 0; c < 2; ++c)
    lds_load16(&Kb[g * 8192 + so + c * 512], kfs + so + c * 512 + lane * 8);

  const f16x8 ones8 = {(f16)1, (f16)1, (f16)1, (f16)1,
                       (f16)1, (f16)1, (f16)1, (f16)1};
  f32x4 lsum[2] = {};  // D[r][q=l15]: per-q denominator, all r identical
  f32x4 o[2][4] = {};

  for (int kt = 0; kt < 16; ++kt) {
    const int cur = kt & 1;
    const bf16* kcur = &Kb[(g * 2 + cur) * 4096];
    __syncthreads();

    if (kt < 15) {
      const size_t nb = (size_t)(kt + 1) * 4096;
#pragma unroll
      for (int c = 0; c < 2; ++c)
        lds_load16(&Kb[(g * 2 + (cur ^ 1)) * 4096 + so + c * 512],
                   kfs + nb + so + c * 512 + lane * 8);
    }

    f32x4 s[2][4] = {};
    __builtin_amdgcn_s_setprio(1);
#pragma unroll
    for (int k2 = 0; k2 < 2; ++k2)
#pragma unroll
      for (int j = 0; j < 4; ++j) {
        const bf16x8 ak = *(const bf16x8*)&kcur[(j * 2 + k2) * 512 + lane * 8];
        s[0][j] = MFMA16(ak, k2 ? bq0b : bq0a, s[0][j]);
        s[1][j] = MFMA16(ak, k2 ? bq1b : bq1a, s[1][j]);
      }
    __builtin_amdgcn_s_setprio(0);

    // in-register softmax + P redistribution, VALU-minimal.
    f16x8 bp[2][2];  // [q-group][k2]
#pragma unroll
    for (int i = 0; i < 2; ++i) {
      uint2t pd[4];
#pragma unroll
      for (int j = 0; j < 4; ++j) {
        const auto lo =
            __builtin_amdgcn_cvt_pkrtz(__builtin_amdgcn_exp2f(s[i][j][0]),
                                       __builtin_amdgcn_exp2f(s[i][j][1]));
        const auto hi =
            __builtin_amdgcn_cvt_pkrtz(__builtin_amdgcn_exp2f(s[i][j][2]),
                                       __builtin_amdgcn_exp2f(s[i][j][3]));
        pd[j][0] = __builtin_bit_cast(unsigned, lo);
        pd[j][1] = __builtin_bit_cast(unsigned, hi);
      }
#pragma unroll
      for (int k2 = 0; k2 < 2; ++k2) {
        uint4t wd;
#pragma unroll
        for (int d = 0; d < 2; ++d) {
          unsigned pa = pd[2 * k2][d], pb = pd[2 * k2 + 1][d];
          asm("v_permlane32_swap_b32 %0, %1" : "+v"(pa), "+v"(pb));
          asm("v_permlane16_swap_b32 %0, %1" : "+v"(pa), "+v"(pb));
          wd[d] = pa;      // bp elements e=0..3 (dword d)
          wd[2 + d] = pb;  // bp elements e=4..7 (dword d)
        }
        bp[i][k2] = __builtin_bit_cast(f16x8, wd);
      }
    }

    // V fragments straight from global (L2-resident), issued HERE — after
    // softmax, where s[2][4] is dead. av liveness = PV cluster only.
    const f16* vt = vfs + (size_t)kt * 4096 + lane * 8;
    f16x8 av[2][4];
#pragma unroll
    for (int k2 = 0; k2 < 2; ++k2)
#pragma unroll
      for (int j = 0; j < 4; ++j)
        av[k2][j] = *(const f16x8*)&vt[(j * 2 + k2) * 512];

    __builtin_amdgcn_s_setprio(1);
#pragma unroll
    for (int k2 = 0; k2 < 2; ++k2) {
#pragma unroll
      for (int j = 0; j < 4; ++j) {
        o[0][j] = MFMA16F(av[k2][j], bp[0][k2], o[0][j]);
        o[1][j] = MFMA16F(av[k2][j], bp[1][k2], o[1][j]);
      }
      // denominator: sums the exact f16 P consumed above (MFMA pipe, free)
      lsum[0] = MFMA16F(ones8, bp[0][k2], lsum[0]);
      lsum[1] = MFMA16F(ones8, bp[1][k2], lsum[1]);
    }
    __builtin_amdgcn_s_setprio(0);
  }

  // in-block combine of the two key-halves; K LDS is dead, reuse it.
  __syncthreads();
  float* ob = (float*)smem;             // [128][68] f32 (padded, 16B rows)
  float* lb = (float*)(smem + 34816);   // [128] f32
  if (g == 1) {
#pragma unroll
    for (int i = 0; i < 2; ++i) {
      const int q = wg * 32 + i * 16 + l15;
#pragma unroll
      for (int j = 0; j < 4; ++j)
        *(f32x4*)&ob[q * 68 + j * 16 + quad * 4] = o[i][j];
      if (quad == 0) lb[q] = lsum[i][0];
    }
  }
  __syncthreads();
  if (g == 0) {
#pragma unroll
    for (int i = 0; i < 2; ++i) {
      const int q = wg * 32 + i * 16 + l15;
      const float inv = 1.f / (lsum[i][0] + lb[q]);
      f16* crow = CTX + (size_t)(b * 2048 + q0 + q) * 1024 + h * 64;
#pragma unroll
      for (int j = 0; j < 4; ++j) {
        const f32x4 ox = o[i][j] + *(const f32x4*)&ob[q * 68 + j * 16 + quad * 4];
        f16x4 ov;
#pragma unroll
        for (int r = 0; r < 4; ++r) ov[r] = (f16)(ox[r] * inv);
        *(f16x4*)&crow[j * 16 + quad * 4] = ov;
      }
    }
  }
}

extern "C" void kernel_launch(void* const* d_in, const int* in_sizes, int n_in,
                              void* d_out, int out_size, void* d_ws,
                              size_t ws_size, hipStream_t stream) {
  const float* x = (const float*)d_in[0];      // [2,2048,1024] fp32
  const float* qkv_w = (const float*)d_in[1];  // [3072,1024] fp32
  const float* qkv_b = (const float*)d_in[2];  // [3072] fp32
  const float* out_w = (const float*)d_in[3];  // [1024,1024] fp32
  const float* out_b = (const float*)d_in[4];  // [1024] fp32
  float* out = (float*)d_out;                  // [2,2048,1024] fp32

  // ws (2B elems): xb 8MB | wqkv 6MB | wout 2MB | qb 8 | KF 8 | VF 8 | ctx 8
  bf16* base = (bf16*)d_ws;
  bf16* xb = base;                                    // [4096][1024] bf16
  bf16* wqkv = base + (size_t)4096 * 1024;            // [3072][1024] bf16
  f16* wout = (f16*)(base + (size_t)7168 * 1024);     // [1024][1024] f16
  bf16* qb = base + (size_t)8192 * 1024;              // [4096][1024] bf16
  bf16* kf = base + (size_t)12288 * 1024;             // frag-native K bf16
  f16* vf = (f16*)(base + (size_t)16384 * 1024);      // frag-native V^T f16
  f16* ctx = (f16*)(base + (size_t)20480 * 1024);     // [4096][1024] f16

  cvt3<<<2097152 / 256, 256, 0, stream>>>(x, qkv_w, out_w, xb, wqkv, wout);

  gemm_qkv<<<768, 256, 0, stream>>>(xb, wqkv, qkv_b, qb, kf, vf);
  attn<<<512, 512, 0, stream>>>(qb, kf, vf, ctx);
  gemm_out<<<512, 256, 0, stream>>>(ctx, wout, out_b, out);
}

// Round 12
// 168.665 us; speedup vs baseline: 1.1629x; 1.0161x over previous
//
#include <hip/hip_runtime.h>

typedef __bf16 bf16;
typedef __bf16 bf16x4 __attribute__((ext_vector_type(4)));
typedef __bf16 bf16x8 __attribute__((ext_vector_type(8)));
typedef _Float16 f16;
typedef _Float16 f16x4 __attribute__((ext_vector_type(4)));
typedef _Float16 f16x8 __attribute__((ext_vector_type(8)));
typedef float f32x4 __attribute__((ext_vector_type(4)));
typedef unsigned int uint2t __attribute__((ext_vector_type(2)));
typedef unsigned int uint4t __attribute__((ext_vector_type(4)));

#define MFMA16(a, b, c) __builtin_amdgcn_mfma_f32_16x16x32_bf16(a, b, c, 0, 0, 0)
#define MFMA16F(a, b, c) __builtin_amdgcn_mfma_f32_16x16x32_f16(a, b, c, 0, 0, 0)

// async global->LDS DMA, 16B/lane; LDS dest = wave-uniform base + lane*16.
__device__ __forceinline__ void lds_load16(void* lds, const void* g) {
  __builtin_amdgcn_global_load_lds(
      (const __attribute__((address_space(1))) unsigned int*)g,
      (__attribute__((address_space(3))) unsigned int*)lds, 16, 0, 0);
}

// fp32 -> {bf16, bf16, f16} bulk convert, all three tensors in one launch.
// out_w goes to f16 (10 mantissa bits vs bf16's 7): |w|<=0.031, f16-safe.
__global__ void cvt3(const float* __restrict__ x, const float* __restrict__ qw,
                     const float* __restrict__ ow, bf16* __restrict__ xb,
                     bf16* __restrict__ qwb, f16* __restrict__ owb) {
  const int i = blockIdx.x * blockDim.x + threadIdx.x;  // 0..2097151
  if (i < 1048576 + 786432) {
    const float* src;
    bf16* dst;
    int k;
    if (i < 1048576) {
      src = x; dst = xb; k = i;
    } else {
      src = qw; dst = qwb; k = i - 1048576;
    }
    const float4 v = ((const float4*)src)[k];
    bf16x4 o;
    o[0] = (bf16)v.x; o[1] = (bf16)v.y; o[2] = (bf16)v.z; o[3] = (bf16)v.w;
    ((bf16x4*)dst)[k] = o;
  } else {
    const int k = i - (1048576 + 786432);
    const float4 v = ((const float4*)ow)[k];
    f16x4 o;
    o[0] = (f16)v.x; o[1] = (f16)v.y; o[2] = (f16)v.z; o[3] = (f16)v.w;
    ((f16x4*)owb)[k] = o;
  }
}

// QKV GEMM, 16x16 MFMA + XOR chunk-swizzled LDS.
//   col<1024  -> Qb[t][col] bf16, PRE-SCALED by 0.125*log2(e)
//   col<2048  -> KF fragment-native bf16 (attn A-frag = base + lane*16B)
//   col>=2048 -> VF fragment-native **f16**, x4-packed along t
// r11: exact revert to the measured-best round-8 configuration (169.39 us).
__global__ __launch_bounds__(256, 2) void gemm_qkv(
    const bf16* __restrict__ A, const bf16* __restrict__ B,
    const float* __restrict__ bias, bf16* __restrict__ Qb,
    bf16* __restrict__ KF, f16* __restrict__ VF) {
  const int K = 1024;
  __shared__ bf16 As[128][64];
  __shared__ bf16 Bs[128][64];
  const int tid = threadIdx.x;
  const int w = tid >> 6, lane = tid & 63;
  const int l15 = lane & 15, quad = lane >> 4;
  const int lr = lane >> 3;  // row within 8-row DMA chunk (= actual_row & 7)
  const int lcs = ((lane & 7) ^ lr) * 8;  // swizzled source col for DMA
  const int sw = l15 & 7;                 // fragment-row & 7 for read side
  const int blk = blockIdx.x;             // 0..767 linear
  const int xslot = blk & 7, rest = blk >> 3;  // rest 0..95
  const int bm = xslot * 4 + (rest & 3);       // 0..31
  const int bn = rest >> 2;                    // 0..23
  const int wm = (w >> 1) * 64, wn = (w & 1) * 64;

  const bf16* Abase = A + (size_t)(bm * 128) * K;
  const bf16* Bbase = B + (size_t)(bn * 128) * K;

  f32x4 acc[4][4] = {};

  for (int k0 = 0; k0 < K; k0 += 64) {
#pragma unroll
    for (int c = 0; c < 4; ++c) {
      const int row = w * 32 + c * 8;  // ≡0 mod 8 -> (row+lr)&7 == lr
      lds_load16(&As[row][0], Abase + (size_t)(row + lr) * K + k0 + lcs);
      lds_load16(&Bs[row][0], Bbase + (size_t)(row + lr) * K + k0 + lcs);
    }
    __syncthreads();
#pragma unroll
    for (int kk = 0; kk < 64; kk += 32) {
      const int cb = kk >> 3;  // logical chunk base: 0 or 4
      bf16x8 am[4], bnf[4];
#pragma unroll
      for (int i = 0; i < 4; ++i)
        am[i] = *(const bf16x8*)&As[wm + i * 16 + l15][((cb + quad) ^ sw) * 8];
#pragma unroll
      for (int j = 0; j < 4; ++j)
        bnf[j] = *(const bf16x8*)&Bs[wn + j * 16 + l15][((cb + quad) ^ sw) * 8];
#pragma unroll
      for (int i = 0; i < 4; ++i)
#pragma unroll
        for (int j = 0; j < 4; ++j)
          acc[i][j] = MFMA16(am[i], bnf[j], acc[i][j]);
    }
    __syncthreads();
  }

  // epilogue: C/D layout col=lane&15, row=quad*4+reg
#pragma unroll
  for (int j = 0; j < 4; ++j) {
    const int gcol = bn * 128 + wn + j * 16 + l15;
    const float bv = bias[gcol];
#pragma unroll
    for (int i = 0; i < 4; ++i) {
      const int t0 = bm * 128 + wm + i * 16 + quad * 4;  // r-consecutive rows
      if (gcol < 1024) {
#pragma unroll
        for (int r = 0; r < 4; ++r)
          Qb[(size_t)(t0 + r) * 1024 + gcol] =
              (bf16)((acc[i][j][r] + bv) * 0.18033688f);  // 0.125*log2e
      } else if (gcol < 2048) {
        const int dhl = gcol - 1024;  // 0..1023
        const int hh = dhl >> 6, dh = dhl & 63;
        const int tl = t0 & 2047, bb = t0 >> 11;
        const size_t frag = ((size_t)(bb * 16 + hh) * 32 + (tl >> 6)) * 8 +
                            ((tl & 63) >> 4) * 2 + (dh >> 5);
        bf16* p = &KF[frag * 512 +
                      (size_t)(((dh >> 3) & 3) * 16 + (tl & 15)) * 8 + (dh & 7)];
#pragma unroll
        for (int r = 0; r < 4; ++r) p[r * 8] = (bf16)(acc[i][j][r] + bv);
      } else {
        const int dhl = gcol - 2048;
        const int hh = dhl >> 6, dh = dhl & 63;
        const int tl = t0 & 2047, bb = t0 >> 11;
        const size_t frag = ((size_t)(bb * 16 + hh) * 32 + (tl >> 6)) * 8 +
                            (dh >> 4) * 2 + ((tl & 63) >> 5);
        f16x4 pv;
#pragma unroll
        for (int r = 0; r < 4; ++r) pv[r] = (f16)(acc[i][j][r] + bv);
        *(f16x4*)&VF[frag * 512 +
                     (size_t)(((tl & 31) >> 3) * 16 + (dh & 15)) * 8 +
                     (tl & 7)] = pv;
      }
    }
  }
}

// Out-proj GEMM, 64x128 tile, same XOR chunk-swizzle. A=ctx, B=out_w in f16.
__global__ __launch_bounds__(256, 2) void gemm_out(
    const f16* __restrict__ A, const f16* __restrict__ B,
    const float* __restrict__ bias, float* __restrict__ Cf) {
  __shared__ f16 As[64][64];
  __shared__ f16 Bs[128][64];
  const int tid = threadIdx.x;
  const int w = tid >> 6, lane = tid & 63;
  const int l15 = lane & 15, quad = lane >> 4;
  const int lr = lane >> 3;
  const int lcs = ((lane & 7) ^ lr) * 8;  // swizzled DMA source col
  const int sw = l15 & 7;
  const int blk = blockIdx.x;  // 0..511 linear
  const int xslot = blk & 7, rest = blk >> 3;  // rest 0..63
  const int bm = xslot * 8 + (rest & 7);       // 0..63
  const int bn = rest >> 3;                    // 0..7

  const f16* Abase = A + (size_t)(bm * 64) * 1024;
  const f16* Bbase = B + (size_t)(bn * 128) * 1024;

  f32x4 acc[4][2] = {};

  for (int k0 = 0; k0 < 1024; k0 += 64) {
#pragma unroll
    for (int c = 0; c < 2; ++c) {
      const int row = w * 16 + c * 8;
      lds_load16(&As[row][0], Abase + (size_t)(row + lr) * 1024 + k0 + lcs);
    }
#pragma unroll
    for (int c = 0; c < 4; ++c) {
      const int row = w * 32 + c * 8;
      lds_load16(&Bs[row][0], Bbase + (size_t)(row + lr) * 1024 + k0 + lcs);
    }
    __syncthreads();
#pragma unroll
    for (int kk = 0; kk < 64; kk += 32) {
      const int cb = kk >> 3;
      f16x8 am[4], bnf[2];
#pragma unroll
      for (int i = 0; i < 4; ++i)
        am[i] = *(const f16x8*)&As[i * 16 + l15][((cb + quad) ^ sw) * 8];
#pragma unroll
      for (int j = 0; j < 2; ++j)
        bnf[j] =
            *(const f16x8*)&Bs[w * 32 + j * 16 + l15][((cb + quad) ^ sw) * 8];
#pragma unroll
      for (int i = 0; i < 4; ++i)
#pragma unroll
        for (int j = 0; j < 2; ++j)
          acc[i][j] = MFMA16F(am[i], bnf[j], acc[i][j]);
    }
    __syncthreads();
  }

#pragma unroll
  for (int j = 0; j < 2; ++j) {
    const int gcol = bn * 128 + w * 32 + j * 16 + l15;
    const float bv = bias[gcol];
#pragma unroll
    for (int i = 0; i < 4; ++i)
#pragma unroll
      for (int r = 0; r < 4; ++r) {
        const int grow = bm * 64 + i * 16 + quad * 4 + r;
        Cf[(size_t)grow * 1024 + gcol] = acc[i][j][r] + bv;
      }
  }
}

// Flash attention v15b (REVERT to measured-best, r8 = 169.39 us total).
// r11 verdict: attn is dependency/latency-paced, not pipe-bound. Evidence:
//  - pipe-sum audit ~1800 cyc/CU-iter of work vs 6450 observed (all <30%).
//  - LDS-traffic -45% (v18, spill-free, verified WRITE_SIZE=8192): 43->45.7
//    us — LDS relief SLOWED it (V loads expose L2 latency the LDS ping-pong
//    hid). Refuted.
//  - occupancy 17->35% (v9->v10): no change. Bank conflicts 3.1M->0: no
//    change. setprio: -0.9 us (noise). V-before-QK: spill catastrophe.
//  - the ONLY win was cutting the serial softmax chain (r8: 52.6->43, -18%).
// Structure: 8 waves = 2 key-groups x 4 waves; group g handles keys
// [g*1024, g*1024+1024) over the same 128 q-rows at 32 q/wave; K/V in LDS
// ping-pong (64KB, 2 blocks/CU); in-reg softmax via cvt_pkrtz + permlane
// swaps; denominator via ones-MFMA; in-block combine of key-halves.
__global__ __launch_bounds__(512, 4) void attn(const bf16* __restrict__ Qb,
                                               const bf16* __restrict__ KF,
                                               const f16* __restrict__ VF,
                                               f16* __restrict__ CTX) {
  // [group][K=0/V=1][pingpong][4096] = 64 KB exactly (V half holds f16)
  __shared__ bf16 KV[2][2][2][4096];
  const int tid = threadIdx.x, w = tid >> 6, lane = tid & 63;
  const int g = w >> 2, wg = w & 3;  // key-group, q-band wave
  const int l15 = lane & 15, quad = lane >> 4;
  const int blk = blockIdx.x;
  const int slot = blk & 7, grp = blk >> 3;
  const int qt = grp & 15, bh = (grp >> 4) * 8 + slot;  // bh 0..31
  const int h = bh & 15, b = bh >> 4;
  const int q0 = qt * 128;

  const bf16* qrow0 =
      Qb + (size_t)(b * 2048 + q0 + wg * 32 + l15) * 1024 + h * 64;
  const bf16* qrow1 = qrow0 + (size_t)16 * 1024;
  const bf16x8 bq0a = *(const bf16x8*)&qrow0[quad * 8];
  const bf16x8 bq0b = *(const bf16x8*)&qrow0[32 + quad * 8];
  const bf16x8 bq1a = *(const bf16x8*)&qrow1[quad * 8];
  const bf16x8 bq1b = *(const bf16x8*)&qrow1[32 + quad * 8];

  const bf16* kfs = KF + (size_t)(b * 16 + h) * 131072 + (size_t)g * 65536;
  const f16* vfs = VF + (size_t)(b * 16 + h) * 131072 + (size_t)g * 65536;
  const int so = wg * 1024;  // 4 waves x 2 chunks x 512 cover the 8KB tile

#pragma unroll
  for (int c = 0; c < 2; ++c) {
    lds_load16(&KV[g][0][0][so + c * 512], kfs + so + c * 512 + lane * 8);
    lds_load16(&KV[g][1][0][so + c * 512], vfs + so + c * 512 + lane * 8);
  }

  const f16x8 ones8 = {(f16)1, (f16)1, (f16)1, (f16)1,
                       (f16)1, (f16)1, (f16)1, (f16)1};
  f32x4 lsum[2] = {};  // D[r][q=l15]: per-q denominator, all r identical
  f32x4 o[2][4] = {};

  for (int kt = 0; kt < 16; ++kt) {
    const int cur = kt & 1;
    const bf16* kcur = &KV[g][0][cur][0];
    const f16* vcur = (const f16*)&KV[g][1][cur][0];
    __syncthreads();

    if (kt < 15) {
      const size_t nb = (size_t)(kt + 1) * 4096;
#pragma unroll
      for (int c = 0; c < 2; ++c) {
        lds_load16(&KV[g][0][cur ^ 1][so + c * 512],
                   kfs + nb + so + c * 512 + lane * 8);
        lds_load16(&KV[g][1][cur ^ 1][so + c * 512],
                   vfs + nb + so + c * 512 + lane * 8);
      }
    }

    f32x4 s[2][4] = {};
#pragma unroll
    for (int k2 = 0; k2 < 2; ++k2)
#pragma unroll
      for (int j = 0; j < 4; ++j) {
        const bf16x8 ak = *(const bf16x8*)&kcur[(j * 2 + k2) * 512 + lane * 8];
        s[0][j] = MFMA16(ak, k2 ? bq0b : bq0a, s[0][j]);
        s[1][j] = MFMA16(ak, k2 ? bq1b : bq1a, s[1][j]);
      }

    // in-register softmax + P redistribution, VALU-minimal.
    f16x8 bp[2][2];  // [q-group][k2]
#pragma unroll
    for (int i = 0; i < 2; ++i) {
      uint2t pd[4];
#pragma unroll
      for (int j = 0; j < 4; ++j) {
        const auto lo =
            __builtin_amdgcn_cvt_pkrtz(__builtin_amdgcn_exp2f(s[i][j][0]),
                                       __builtin_amdgcn_exp2f(s[i][j][1]));
        const auto hi =
            __builtin_amdgcn_cvt_pkrtz(__builtin_amdgcn_exp2f(s[i][j][2]),
                                       __builtin_amdgcn_exp2f(s[i][j][3]));
        pd[j][0] = __builtin_bit_cast(unsigned, lo);
        pd[j][1] = __builtin_bit_cast(unsigned, hi);
      }
#pragma unroll
      for (int k2 = 0; k2 < 2; ++k2) {
        uint4t wd;
#pragma unroll
        for (int d = 0; d < 2; ++d) {
          unsigned pa = pd[2 * k2][d], pb = pd[2 * k2 + 1][d];
          asm("v_permlane32_swap_b32 %0, %1" : "+v"(pa), "+v"(pb));
          asm("v_permlane16_swap_b32 %0, %1" : "+v"(pa), "+v"(pb));
          wd[d] = pa;      // bp elements e=0..3 (dword d)
          wd[2 + d] = pb;  // bp elements e=4..7 (dword d)
        }
        bp[i][k2] = __builtin_bit_cast(f16x8, wd);
      }
    }

#pragma unroll
    for (int k2 = 0; k2 < 2; ++k2) {
#pragma unroll
      for (int j = 0; j < 4; ++j) {
        const f16x8 av = *(const f16x8*)&vcur[(j * 2 + k2) * 512 + lane * 8];
        o[0][j] = MFMA16F(av, bp[0][k2], o[0][j]);
        o[1][j] = MFMA16F(av, bp[1][k2], o[1][j]);
      }
      // denominator: sums the exact f16 P consumed above (MFMA pipe, free)
      lsum[0] = MFMA16F(ones8, bp[0][k2], lsum[0]);
      lsum[1] = MFMA16F(ones8, bp[1][k2], lsum[1]);
    }
  }

  // in-block combine of the two key-halves; KV LDS is dead, reuse it.
  __syncthreads();
  float* ob = (float*)&KV[0][0][0][0];  // [128][68] f32 (padded, 16B rows)
  float* lb = ob + 128 * 68;            // [128] f32
  if (g == 1) {
#pragma unroll
    for (int i = 0; i < 2; ++i) {
      const int q = wg * 32 + i * 16 + l15;
#pragma unroll
      for (int j = 0; j < 4; ++j)
        *(f32x4*)&ob[q * 68 + j * 16 + quad * 4] = o[i][j];
      if (quad == 0) lb[q] = lsum[i][0];
    }
  }
  __syncthreads();
  if (g == 0) {
#pragma unroll
    for (int i = 0; i < 2; ++i) {
      const int q = wg * 32 + i * 16 + l15;
      const float inv = 1.f / (lsum[i][0] + lb[q]);
      f16* crow = CTX + (size_t)(b * 2048 + q0 + q) * 1024 + h * 64;
#pragma unroll
      for (int j = 0; j < 4; ++j) {
        const f32x4 ox = o[i][j] + *(const f32x4*)&ob[q * 68 + j * 16 + quad * 4];
        f16x4 ov;
#pragma unroll
        for (int r = 0; r < 4; ++r) ov[r] = (f16)(ox[r] * inv);
        *(f16x4*)&crow[j * 16 + quad * 4] = ov;
      }
    }
  }
}

extern "C" void kernel_launch(void* const* d_in, const int* in_sizes, int n_in,
                              void* d_out, int out_size, void* d_ws,
                              size_t ws_size, hipStream_t stream) {
  const float* x = (const float*)d_in[0];      // [2,2048,1024] fp32
  const float* qkv_w = (const float*)d_in[1];  // [3072,1024] fp32
  const float* qkv_b = (const float*)d_in[2];  // [3072] fp32
  const float* out_w = (const float*)d_in[3];  // [1024,1024] fp32
  const float* out_b = (const float*)d_in[4];  // [1024] fp32
  float* out = (float*)d_out;                  // [2,2048,1024] fp32

  // ws (2B elems): xb 8MB | wqkv 6MB | wout 2MB | qb 8 | KF 8 | VF 8 | ctx 8
  bf16* base = (bf16*)d_ws;
  bf16* xb = base;                                    // [4096][1024] bf16
  bf16* wqkv = base + (size_t)4096 * 1024;            // [3072][1024] bf16
  f16* wout = (f16*)(base + (size_t)7168 * 1024);     // [1024][1024] f16
  bf16* qb = base + (size_t)8192 * 1024;              // [4096][1024] bf16
  bf16* kf = base + (size_t)12288 * 1024;             // frag-native K bf16
  f16* vf = (f16*)(base + (size_t)16384 * 1024);      // frag-native V^T f16
  f16* ctx = (f16*)(base + (size_t)20480 * 1024);     // [4096][1024] f16

  cvt3<<<2097152 / 256, 256, 0, stream>>>(x, qkv_w, out_w, xb, wqkv, wout);

  gemm_qkv<<<768, 256, 0, stream>>>(xb, wqkv, qkv_b, qb, kf, vf);
  attn<<<512, 512, 0, stream>>>(qb, kf, vf, ctx);
  gemm_out<<<512, 256, 0, stream>>>(ctx, wout, out_b, out);
}